// Round 4
// baseline (1251.127 us; speedup 1.0000x reference)
//
#include <hip/hip_runtime.h>
#include <hip/hip_fp16.h>
#include <math.h>

// GatedGraphXBias: E=12, T=2048, H=64, IN=128, 10 iterations.
// Round 4: bmm v3 — tiled pre-swizzled fp16 hi/lo layouts + global_load_lds
// width-16 staging + 2-phase double-buffered pipeline + KSPLIT=4.
// fp32 fallback path if ws is too small.

constexpr int T   = 2048;
constexpr int H   = 64;
constexpr int E   = 12;
constexpr int FIN = 128;
constexpr int K3  = 192;   // 3*H
constexpr int ITER = 10;
constexpr int KSPLIT = 4;
constexpr int KSEG = T / KSPLIT;     // 512
constexpr int NT_PER_KZ = KSEG / 64; // 8 K-tiles per block
// tile: 64 rows x 64 halves = 64 rows x 8 chunks x 16B = 8192 B = 4096 ushorts
constexpr int TILE_US = 4096;

// hi = fp16(SH*a); lo = fp16(SL*(SH*a - hi)); a ~= (hi + lo/SL)/SH, err ~2^-22*|a|
// P = accH/SH^2 + accL/(SH^2*SL)
#define SH   64.0f
#define SL   4096.0f
#define INV_HH (1.0f / 4096.0f)        // 1/SH^2
#define INV_HL (1.0f / 16777216.0f)    // 1/(SH^2*SL)

typedef _Float16 half8 __attribute__((ext_vector_type(8)));
typedef float f32x4 __attribute__((ext_vector_type(4)));

typedef const __attribute__((address_space(1))) unsigned int* gas_uint_ptr;
typedef __attribute__((address_space(3))) unsigned int* las_uint_ptr;

__device__ __forceinline__ void gload_lds16(const void* g, void* l) {
    __builtin_amdgcn_global_load_lds((gas_uint_ptr)g, (las_uint_ptr)l, 16, 0, 0);
}

__device__ __forceinline__ float sigmoidf_(float x) {
    return 1.0f / (1.0f + __expf(-x));
}
__device__ __forceinline__ void split16(float a, ushort& hi, ushort& lo) {
    float as = a * SH;
    __half h1 = __float2half(as);
    float r = (as - __half2float(h1)) * SL;
    __half h2 = __float2half(r);
    hi = __half_as_ushort(h1);
    lo = __half_as_ushort(h2);
}

// ---------------- iteration-invariant prep ----------------

// constv[k] = sum_{e,h} ba[e,h]*W[e,h,k] + E*bw[k]   (one block per k)
__global__ __launch_bounds__(256) void const_kernel(const float* __restrict__ ba,
                                                    const float* __restrict__ W,
                                                    const float* __restrict__ bw,
                                                    float* __restrict__ constv) {
    __shared__ float red[256];
    const int k = blockIdx.x;
    const int tid = threadIdx.x;
    float s = 0.0f;
    for (int eh = tid; eh < E * H; eh += 256)
        s += ba[eh] * W[(size_t)eh * K3 + k];
    red[tid] = s;
    __syncthreads();
    for (int off = 128; off > 0; off >>= 1) {
        if (tid < off) red[tid] += red[tid + off];
        __syncthreads();
    }
    if (tid == 0) constv[k] = red[0] + (float)E * bw[k];
}

// base[t,k] = constv[k] + sum_j x[t,j]*iw[j,k]
__global__ __launch_bounds__(256) void base_kernel(const float* __restrict__ x,
                                                   const float* __restrict__ iw,
                                                   const float* __restrict__ constv,
                                                   float* __restrict__ base) {
    int idx = blockIdx.x * 256 + threadIdx.x;
    int t = idx / K3, k = idx % K3;
    float acc = constv[k];
    const float* xr = x + (size_t)t * FIN;
    for (int j = 0; j < FIN; ++j)
        acc = fmaf(xr[j], iw[(size_t)j * K3 + k], acc);
    base[idx] = acc;
}

// edgeT tiled+swizzled: tile idx = (e*32 + tb)*32 + sb; within tile, linear
// position (row=t-local, c) holds logical s-chunk (c ^ (row&7)), 8 halves.
// grid (32 tb, 32 sb, E), block 256
__global__ __launch_bounds__(256) void edgeT_kernel(const float* __restrict__ edge,
                                                    ushort* __restrict__ ehi,
                                                    ushort* __restrict__ elo) {
    __shared__ float til[64][65];    // [s-local][t-local]
    const int t0 = blockIdx.x * 64;
    const int s0 = blockIdx.y * 64;
    const int e  = blockIdx.z;
    const int tid = threadIdx.x;
    const float* eb = edge + ((size_t)e * T + s0) * T + t0;
    #pragma unroll
    for (int p = 0; p < 4; ++p) {
        int idx = tid + p * 256;
        int r = idx >> 4, c4 = (idx & 15) << 2;       // r = s-local, c = t-local
        float4 v = *reinterpret_cast<const float4*>(eb + (size_t)r * T + c4);
        til[r][c4] = v.x; til[r][c4 + 1] = v.y; til[r][c4 + 2] = v.z; til[r][c4 + 3] = v.w;
    }
    __syncthreads();
    size_t tbase = ((size_t)(e * 32 + blockIdx.x) * 32 + blockIdx.y) * TILE_US;
    #pragma unroll
    for (int p = 0; p < 2; ++p) {
        int q = tid + p * 256;          // 0..511
        int tt = q >> 3, c = q & 7;
        int lc = c ^ (tt & 7);          // logical s-chunk stored here
        ushort hb[8], lb[8];
        #pragma unroll
        for (int j = 0; j < 8; ++j)
            split16(til[lc * 8 + j][tt], hb[j], lb[j]);
        *reinterpret_cast<uint4*>(ehi + tbase + q * 8) = *reinterpret_cast<uint4*>(hb);
        *reinterpret_cast<uint4*>(elo + tbase + q * 8) = *reinterpret_cast<uint4*>(lb);
    }
}

// hT tiled+swizzled: tile idx = sb (= t-tile of h rows); (row=h, c) holds
// logical t-chunk (c ^ (row&7)). grid 32, block 256
__global__ __launch_bounds__(256) void hsplit_kernel(const float* __restrict__ hbuf,
                                                     ushort* __restrict__ hhi,
                                                     ushort* __restrict__ hlo) {
    __shared__ float til[64][65];    // [t-local][h]
    const int t0 = blockIdx.x * 64;
    const int tid = threadIdx.x;
    #pragma unroll
    for (int p = 0; p < 4; ++p) {
        int idx = tid + p * 256;
        int r = idx >> 4, c4 = (idx & 15) << 2;
        float4 v = *reinterpret_cast<const float4*>(hbuf + (size_t)(t0 + r) * H + c4);
        til[r][c4] = v.x; til[r][c4 + 1] = v.y; til[r][c4 + 2] = v.z; til[r][c4 + 3] = v.w;
    }
    __syncthreads();
    size_t tbase = (size_t)blockIdx.x * TILE_US;
    #pragma unroll
    for (int p = 0; p < 2; ++p) {
        int q = tid + p * 256;
        int hh = q >> 3, c = q & 7;
        int lc = c ^ (hh & 7);          // logical t-chunk stored here
        ushort hb[8], lb[8];
        #pragma unroll
        for (int j = 0; j < 8; ++j)
            split16(til[lc * 8 + j][hh], hb[j], lb[j]);
        *reinterpret_cast<uint4*>(hhi + tbase + q * 8) = *reinterpret_cast<uint4*>(hb);
        *reinterpret_cast<uint4*>(hlo + tbase + q * 8) = *reinterpret_cast<uint4*>(lb);
    }
}

// ---------------- MFMA bmm v3 ----------------
// P2[kz][e][t][h] = sum_{s in seg kz} edgeT[e][t][s] * h[s][h]
// grid (32 tb, E, KSPLIT), block 256 (4 waves, 2x2 wave grid, 32x32 per wave)
__global__ __launch_bounds__(256) void bmm_mfma_kernel(
        const ushort* __restrict__ Ahi, const ushort* __restrict__ Alo,
        const ushort* __restrict__ Bhi, const ushort* __restrict__ Blo,
        float* __restrict__ P2) {
    __shared__ __align__(1024) char smem[2][4][8192];   // [dbuf][Ah,Al,Bh,Bl]
    const int tb = blockIdx.x;
    const int e  = blockIdx.y;
    const int kz = blockIdx.z;
    const int tid  = threadIdx.x;
    const int lane = tid & 63;
    const int w    = tid >> 6;
    const int wm = w >> 1, wn = w & 1;

    const char* gsrc[4];
    gsrc[0] = (const char*)(Ahi + ((size_t)(e * 32 + tb) * 32 + kz * NT_PER_KZ) * TILE_US);
    gsrc[1] = (const char*)(Alo + ((size_t)(e * 32 + tb) * 32 + kz * NT_PER_KZ) * TILE_US);
    gsrc[2] = (const char*)(Bhi + (size_t)(kz * NT_PER_KZ) * TILE_US);
    gsrc[3] = (const char*)(Blo + (size_t)(kz * NT_PER_KZ) * TILE_US);

    // fragment LDS byte offsets (loop-invariant): row*128 + ((kc ^ (row&7))<<4)
    int offA[2][2], offB[2][2];
    #pragma unroll
    for (int mi = 0; mi < 2; ++mi)
        #pragma unroll
        for (int u = 0; u < 2; ++u) {
            int rowA = wm * 32 + mi * 16 + (lane & 15);
            int rowB = wn * 32 + mi * 16 + (lane & 15);
            int kc = u * 4 + (lane >> 4);
            offA[mi][u] = rowA * 128 + ((kc ^ (rowA & 7)) << 4);
            offB[mi][u] = rowB * 128 + ((kc ^ (rowB & 7)) << 4);
        }

    f32x4 accH[2][2], accL[2][2];
    #pragma unroll
    for (int i = 0; i < 2; ++i)
        #pragma unroll
        for (int j = 0; j < 2; ++j) { accH[i][j] = (f32x4)(0.0f); accL[i][j] = (f32x4)(0.0f); }

    // stage all 4 matrices of K-tile kt into buffer b
    auto stage_all = [&](int b, int kt) {
        #pragma unroll
        for (int m = 0; m < 4; ++m) {
            const char* g = gsrc[m] + (size_t)kt * 8192;
            #pragma unroll
            for (int p = 0; p < 2; ++p) {
                int q = tid + p * 256;                 // chunk 0..511
                gload_lds16(g + q * 16, &smem[b][m][(q >> 6) << 10]);
            }
        }
    };

    auto compute = [&](int b) {
        const char* bAh = smem[b][0];
        const char* bAl = smem[b][1];
        const char* bBh = smem[b][2];
        const char* bBl = smem[b][3];
        half8 fah[2][2], fal[2][2], fbh[2][2], fbl[2][2];
        #pragma unroll
        for (int mi = 0; mi < 2; ++mi)
            #pragma unroll
            for (int u = 0; u < 2; ++u) {
                fah[mi][u] = *reinterpret_cast<const half8*>(bAh + offA[mi][u]);
                fal[mi][u] = *reinterpret_cast<const half8*>(bAl + offA[mi][u]);
                fbh[mi][u] = *reinterpret_cast<const half8*>(bBh + offB[mi][u]);
                fbl[mi][u] = *reinterpret_cast<const half8*>(bBl + offB[mi][u]);
            }
        #pragma unroll
        for (int u = 0; u < 2; ++u)
            #pragma unroll
            for (int mi = 0; mi < 2; ++mi)
                #pragma unroll
                for (int ni = 0; ni < 2; ++ni) {
                    accH[mi][ni] = __builtin_amdgcn_mfma_f32_16x16x32_f16(
                        fah[mi][u], fbh[ni][u], accH[mi][ni], 0, 0, 0);
                    accL[mi][ni] = __builtin_amdgcn_mfma_f32_16x16x32_f16(
                        fah[mi][u], fbl[ni][u], accL[mi][ni], 0, 0, 0);
                    accL[mi][ni] = __builtin_amdgcn_mfma_f32_16x16x32_f16(
                        fal[mi][u], fbh[ni][u], accL[mi][ni], 0, 0, 0);
                }
    };

    int cur = 0;
    stage_all(0, 0);
    __syncthreads();                       // tile 0 resident
    for (int kt = 0; kt < NT_PER_KZ; ++kt) {
        if (kt < NT_PER_KZ - 1) stage_all(cur ^ 1, kt + 1);
        compute(cur);
        __syncthreads();                   // drains next-tile loads; all waves done with cur
        cur ^= 1;
    }

    const int t0 = tb * 64;
    float* outp = P2 + (((size_t)kz * E + e) * T + t0) * H;
    #pragma unroll
    for (int mi = 0; mi < 2; ++mi)
        #pragma unroll
        for (int ni = 0; ni < 2; ++ni)
            #pragma unroll
            for (int j = 0; j < 4; ++j) {
                int row = wm * 32 + mi * 16 + (lane >> 4) * 4 + j;
                int col = wn * 32 + ni * 16 + (lane & 15);
                outp[(size_t)row * H + col] =
                    accH[mi][ni][j] * INV_HH + accL[mi][ni][j] * INV_HL;
            }
}

// ---------------- fp32 fallback bmm ----------------
constexpr int BMM_BM = 64;
constexpr int BMM_BK = 32;
__global__ __launch_bounds__(128) void bmm_kernel(const float* __restrict__ edge,
                                                  const float* __restrict__ hbuf,
                                                  float* __restrict__ P) {
    __shared__ float As[BMM_BK][68];
    __shared__ float Bs[BMM_BK][68];
    const int e  = blockIdx.y;
    const int t0 = blockIdx.x * BMM_BM;
    const int tid = threadIdx.x;
    const int ty = tid >> 4;
    const int tx = tid & 15;
    const float* eb = edge + (size_t)e * T * T;
    float acc[8][4];
    #pragma unroll
    for (int i = 0; i < 8; ++i)
        #pragma unroll
        for (int j = 0; j < 4; ++j) acc[i][j] = 0.0f;
    for (int s0 = 0; s0 < T; s0 += BMM_BK) {
        #pragma unroll
        for (int p = 0; p < 4; ++p) {
            int idx = tid + p * 128;
            int r = idx >> 4, c4 = (idx & 15) << 2;
            *reinterpret_cast<float4*>(&As[r][c4]) =
                *reinterpret_cast<const float4*>(eb + (size_t)(s0 + r) * T + t0 + c4);
            *reinterpret_cast<float4*>(&Bs[r][c4]) =
                *reinterpret_cast<const float4*>(hbuf + (size_t)(s0 + r) * H + c4);
        }
        __syncthreads();
        #pragma unroll
        for (int k = 0; k < BMM_BK; ++k) {
            float a[8], b[4];
            *reinterpret_cast<float4*>(&a[0]) = *reinterpret_cast<const float4*>(&As[k][ty * 8]);
            *reinterpret_cast<float4*>(&a[4]) = *reinterpret_cast<const float4*>(&As[k][ty * 8 + 4]);
            *reinterpret_cast<float4*>(&b[0]) = *reinterpret_cast<const float4*>(&Bs[k][tx * 4]);
            #pragma unroll
            for (int i = 0; i < 8; ++i)
                #pragma unroll
                for (int j = 0; j < 4; ++j)
                    acc[i][j] = fmaf(a[i], b[j], acc[i][j]);
        }
        __syncthreads();
    }
    float* pb = P + ((size_t)e * T + t0) * H;
    #pragma unroll
    for (int i = 0; i < 8; ++i) {
        float4 v = make_float4(acc[i][0], acc[i][1], acc[i][2], acc[i][3]);
        *reinterpret_cast<float4*>(pb + (size_t)(ty * 8 + i) * H + tx * 4) = v;
    }
}

// ---------------- projection ----------------
// partial[e,t,k] = sum_h (sum_kz P2[kz,e,t,h]) * W[e,h,k]
__global__ __launch_bounds__(256) void proj_kernel(const float* __restrict__ P2,
                                                   const float* __restrict__ W,
                                                   float* __restrict__ partial,
                                                   int ksplit) {
    __shared__ float Ps[64][68];
    __shared__ float Ws[H][K3];
    const int e  = blockIdx.y;
    const int t0 = blockIdx.x * 64;
    const int tid = threadIdx.x;
    const float* pb = P2 + ((size_t)e * T + t0) * H;
    const size_t SL2 = (size_t)E * T * H;
    const float* wb = W + (size_t)e * H * K3;
    #pragma unroll
    for (int p = 0; p < 4; ++p) {
        int idx = tid + p * 256;
        int r = idx >> 4, c4 = (idx & 15) << 2;
        float4 v = *reinterpret_cast<const float4*>(pb + (size_t)r * H + c4);
        for (int z = 1; z < ksplit; ++z) {
            float4 u = *reinterpret_cast<const float4*>(pb + (size_t)z * SL2 + (size_t)r * H + c4);
            v.x += u.x; v.y += u.y; v.z += u.z; v.w += u.w;
        }
        *reinterpret_cast<float4*>(&Ps[r][c4]) = v;
    }
    #pragma unroll
    for (int p = 0; p < 12; ++p) {
        int idx = tid + p * 256;
        int r = idx / 48, c4 = (idx % 48) << 2;
        *reinterpret_cast<float4*>(&Ws[r][c4]) =
            *reinterpret_cast<const float4*>(wb + (size_t)r * K3 + c4);
    }
    __syncthreads();
    const int ty = tid >> 4;
    const int tx = tid & 15;
    float acc[4][12];
    #pragma unroll
    for (int i = 0; i < 4; ++i)
        #pragma unroll
        for (int c = 0; c < 12; ++c) acc[i][c] = 0.0f;
    for (int h = 0; h < H; ++h) {
        float a[4], b[12];
        #pragma unroll
        for (int i = 0; i < 4; ++i) a[i] = Ps[ty * 4 + i][h];
        *reinterpret_cast<float4*>(&b[0]) = *reinterpret_cast<const float4*>(&Ws[h][tx * 12]);
        *reinterpret_cast<float4*>(&b[4]) = *reinterpret_cast<const float4*>(&Ws[h][tx * 12 + 4]);
        *reinterpret_cast<float4*>(&b[8]) = *reinterpret_cast<const float4*>(&Ws[h][tx * 12 + 8]);
        #pragma unroll
        for (int i = 0; i < 4; ++i)
            #pragma unroll
            for (int c = 0; c < 12; ++c)
                acc[i][c] = fmaf(a[i], b[c], acc[i][c]);
    }
    float* ob = partial + ((size_t)e * T + t0) * K3;
    #pragma unroll
    for (int i = 0; i < 4; ++i) {
        float* orow = ob + (size_t)(ty * 4 + i) * K3 + tx * 12;
        *reinterpret_cast<float4*>(orow)     = make_float4(acc[i][0], acc[i][1], acc[i][2],  acc[i][3]);
        *reinterpret_cast<float4*>(orow + 4) = make_float4(acc[i][4], acc[i][5], acc[i][6],  acc[i][7]);
        *reinterpret_cast<float4*>(orow + 8) = make_float4(acc[i][8], acc[i][9], acc[i][10], acc[i][11]);
    }
}

// ---------------- GRU update ----------------
__global__ __launch_bounds__(256) void gru_kernel(float* __restrict__ hbuf,
                                                  const float* __restrict__ partial,
                                                  const float* __restrict__ base,
                                                  const float* __restrict__ uzur,
                                                  const float* __restrict__ uhm) {
    __shared__ float Uzr[H][2 * H];
    __shared__ float Uh[H][H];
    __shared__ float hrow[16][68];
    __shared__ float rh[16][68];
    const int t0 = blockIdx.x * 16;
    const int tid = threadIdx.x;
    #pragma unroll
    for (int p = 0; p < 8; ++p) {
        int idx = tid + p * 256;
        int r = idx >> 5, c4 = (idx & 31) << 2;
        *reinterpret_cast<float4*>(&Uzr[r][c4]) =
            *reinterpret_cast<const float4*>(uzur + (size_t)r * 2 * H + c4);
    }
    #pragma unroll
    for (int p = 0; p < 4; ++p) {
        int idx = tid + p * 256;
        int r = idx >> 4, c4 = (idx & 15) << 2;
        *reinterpret_cast<float4*>(&Uh[r][c4]) =
            *reinterpret_cast<const float4*>(uhm + (size_t)r * H + c4);
    }
    {
        int r = tid >> 4, c4 = (tid & 15) << 2;
        *reinterpret_cast<float4*>(&hrow[r][c4]) =
            *reinterpret_cast<const float4*>(hbuf + (size_t)(t0 + r) * H + c4);
    }
    __syncthreads();
    const int row = tid >> 4, cg = tid & 15;
    const int t = t0 + row, j0 = cg * 4;

    float az[4], ar[4], ah[4];
    const float* bp = base + (size_t)t * K3;
    {
        float4 b0 = *reinterpret_cast<const float4*>(bp + j0);
        float4 b1 = *reinterpret_cast<const float4*>(bp + 64 + j0);
        float4 b2 = *reinterpret_cast<const float4*>(bp + 128 + j0);
        az[0]=b0.x; az[1]=b0.y; az[2]=b0.z; az[3]=b0.w;
        ar[0]=b1.x; ar[1]=b1.y; ar[2]=b1.z; ar[3]=b1.w;
        ah[0]=b2.x; ah[1]=b2.y; ah[2]=b2.z; ah[3]=b2.w;
    }
    #pragma unroll
    for (int e = 0; e < E; ++e) {
        const float* pp = partial + ((size_t)e * T + t) * K3;
        float4 v0 = *reinterpret_cast<const float4*>(pp + j0);
        float4 v1 = *reinterpret_cast<const float4*>(pp + 64 + j0);
        float4 v2 = *reinterpret_cast<const float4*>(pp + 128 + j0);
        az[0]+=v0.x; az[1]+=v0.y; az[2]+=v0.z; az[3]+=v0.w;
        ar[0]+=v1.x; ar[1]+=v1.y; ar[2]+=v1.z; ar[3]+=v1.w;
        ah[0]+=v2.x; ah[1]+=v2.y; ah[2]+=v2.z; ah[3]+=v2.w;
    }
    float hv[4];
    #pragma unroll
    for (int c = 0; c < 4; ++c) hv[c] = hrow[row][j0 + c];

    float uz[4] = {0,0,0,0}, ur[4] = {0,0,0,0};
    for (int hh = 0; hh < H; ++hh) {
        float hs = hrow[row][hh];
        #pragma unroll
        for (int c = 0; c < 4; ++c) {
            uz[c] = fmaf(hs, Uzr[hh][j0 + c], uz[c]);
            ur[c] = fmaf(hs, Uzr[hh][64 + j0 + c], ur[c]);
        }
    }
    float z[4], rr[4];
    #pragma unroll
    for (int c = 0; c < 4; ++c) {
        z[c]  = sigmoidf_(az[c] + uz[c]);
        rr[c] = sigmoidf_(ar[c] + ur[c]);
        rh[row][j0 + c] = rr[c] * hv[c];
    }
    __syncthreads();
    float uht[4] = {0,0,0,0};
    for (int hh = 0; hh < H; ++hh) {
        float rs = rh[row][hh];
        #pragma unroll
        for (int c = 0; c < 4; ++c)
            uht[c] = fmaf(rs, Uh[hh][j0 + c], uht[c]);
    }
    float hn[4];
    #pragma unroll
    for (int c = 0; c < 4; ++c) {
        float ht = tanhf(ah[c] + uht[c]);
        hn[c] = (1.0f - z[c]) * hv[c] + z[c] * ht;
    }
    *reinterpret_cast<float4*>(hbuf + (size_t)t * H + j0) =
        make_float4(hn[0], hn[1], hn[2], hn[3]);
}

extern "C" void kernel_launch(void* const* d_in, const int* in_sizes, int n_in,
                              void* d_out, int out_size, void* d_ws, size_t ws_size,
                              hipStream_t stream) {
    const float* x    = (const float*)d_in[0];
    const float* h0   = (const float*)d_in[1];
    const float* edge = (const float*)d_in[2];
    const float* ba   = (const float*)d_in[3];
    const float* W    = (const float*)d_in[4];
    const float* uzur = (const float*)d_in[5];
    const float* uhm  = (const float*)d_in[6];
    const float* iw   = (const float*)d_in[7];
    const float* bw   = (const float*)d_in[8];
    float* out = (float*)d_out;

    float* ws = (float*)d_ws;
    float* hbuf    = ws;                                   // T*H
    float* basep   = hbuf + (size_t)T * H;                 // T*K3
    float* constv  = basep + (size_t)T * K3;               // 256
    float* P2      = constv + 256;                         // KSPLIT*E*T*H
    float* partial = P2 + (size_t)KSPLIT * E * T * H;      // E*T*K3
    ushort* hT_hi  = (ushort*)(partial + (size_t)E * T * K3);  // H*T (tiled)
    ushort* hT_lo  = hT_hi + (size_t)H * T;
    ushort* eT_hi  = hT_lo + (size_t)H * T;                // E*T*T (tiled)
    ushort* eT_lo  = eT_hi + (size_t)E * T * T;

    const size_t NEED_MFMA =
        (size_t)((char*)(eT_lo + (size_t)E * T * T) - (char*)d_ws);
    const bool useMfma = ws_size >= NEED_MFMA;

    hipMemcpyAsync(hbuf, h0, sizeof(float) * T * H, hipMemcpyDeviceToDevice, stream);
    const_kernel<<<K3, 256, 0, stream>>>(ba, W, bw, constv);
    base_kernel<<<(T * K3) / 256, 256, 0, stream>>>(x, iw, constv, basep);

    if (useMfma) {
        edgeT_kernel<<<dim3(32, 32, E), 256, 0, stream>>>(edge, eT_hi, eT_lo);
        for (int it = 0; it < ITER; ++it) {
            hsplit_kernel<<<32, 256, 0, stream>>>(hbuf, hT_hi, hT_lo);
            bmm_mfma_kernel<<<dim3(32, E, KSPLIT), 256, 0, stream>>>(
                eT_hi, eT_lo, hT_hi, hT_lo, P2);
            proj_kernel<<<dim3(32, E), 256, 0, stream>>>(P2, W, partial, KSPLIT);
            gru_kernel<<<T / 16, 256, 0, stream>>>(hbuf, partial, basep, uzur, uhm);
        }
    } else {
        for (int it = 0; it < ITER; ++it) {
            bmm_kernel<<<dim3(T / BMM_BM, E), 128, 0, stream>>>(edge, hbuf, P2);
            proj_kernel<<<dim3(32, E), 256, 0, stream>>>(P2, W, partial, 1);
            gru_kernel<<<T / 16, 256, 0, stream>>>(hbuf, partial, basep, uzur, uhm);
        }
    }
    hipMemcpyAsync(out, hbuf, sizeof(float) * T * H, hipMemcpyDeviceToDevice, stream);
}